// Round 6
// baseline (1535.548 us; speedup 1.0000x reference)
//
#include <hip/hip_runtime.h>
#include <hip/hip_bf16.h>
#include <math.h>

// ============================================================================
// ImprovedTransformerBlock on MI355X.  R9 = R8 with the sparse-MoE epilogue
// DE-ATOMIZED: R8's 16.7M fp32 atomicAdds (measured ~207us, ~L2 atomic
// throughput bound) are replaced by rank-split plain stores:
//   gate_kernel  -> perm entry = padded_row | (rank<<15)  (rank 0 = top-1)
//   gather GEMM  -> buf[rank][token][col] = gelu(acc+bias_e)*combine  (unique
//                   (token,rank,col) per store; full coverage, no init)
//   moe_add      -> out += buf0 + buf1  (float4, ~134MB traffic ~25us)
// bufs live in BIG (67MB <= 100MB; Sp dead, h1 not yet live).
// Everything else identical to R8 (chain-broken MFMA, XCD swizzle,
// counted-vmcnt dbuf, sparse gathered expert GEMM).
// ============================================================================

typedef unsigned short UST;
typedef unsigned int uint32;
typedef float f32x4 __attribute__((ext_vector_type(4)));
using s16x8 = __attribute__((ext_vector_type(8))) short;   // 8 bf16 = 4 VGPRs

#define DEV __device__ __forceinline__
#define MFMA16 __builtin_amdgcn_mfma_f32_16x16x32_bf16

// async global->LDS, 16 bytes/lane; lds dst is wave-uniform base + lane*16
#define GLL(g, l) __builtin_amdgcn_global_load_lds( \
    (const __attribute__((address_space(1))) unsigned int*)(g), \
    (__attribute__((address_space(3))) unsigned int*)(l), 16, 0, 0)

// raw sync primitives (counted vmcnt pipeline) — asm with memory clobber so
// compiler-generated ds_read/GLL cannot migrate across them.
#define BARRIER()  asm volatile("s_barrier" ::: "memory")
#define LGKM0()    asm volatile("s_waitcnt lgkmcnt(0)" ::: "memory")
#define VM0()      asm volatile("s_waitcnt vmcnt(0)" ::: "memory")

DEV UST f2bf(float f) {                       // round-to-nearest-even fp32->bf16
    uint32 u = __float_as_uint(f);
    u += 0x7FFFu + ((u >> 16) & 1u);
    return (UST)(u >> 16);
}
DEV float bf2f(UST h) { return __uint_as_float(((uint32)h) << 16); }
DEV float gelu_f(float x) { return 0.5f * x * (1.0f + erff(x * 0.7071067811865475f)); }

// ---------------------------------------------------------------------------
// LayerNorm -> split bf16 (hi/lo), conv-padded row layout: row(t)=t+2+4*(t>>12)
// ---------------------------------------------------------------------------
__global__ void ln_split_kernel(const float* __restrict__ x,
                                const float* __restrict__ g, const float* __restrict__ b,
                                UST* __restrict__ oh, UST* __restrict__ ol)
{
    const int t = blockIdx.x;
    const int tid = threadIdx.x;
    const float4 v = ((const float4*)(x + (long)t * 1024))[tid];
    float s = v.x + v.y + v.z + v.w;
    float q = v.x * v.x + v.y * v.y + v.z * v.z + v.w * v.w;
    for (int o = 32; o > 0; o >>= 1) { s += __shfl_xor(s, o, 64); q += __shfl_xor(q, o, 64); }
    __shared__ float ss[4], sq[4];
    const int wave = tid >> 6, lane = tid & 63;
    if (lane == 0) { ss[wave] = s; sq[wave] = q; }
    __syncthreads();
    s = ss[0] + ss[1] + ss[2] + ss[3];
    q = sq[0] + sq[1] + sq[2] + sq[3];
    const float mean = s * (1.0f / 1024.0f);
    const float var = q * (1.0f / 1024.0f) - mean * mean;
    const float rstd = 1.0f / sqrtf(var + 1e-5f);
    const long row = (long)t + 2 + 4 * (t >> 12);
    UST* ph = oh + row * 1024 + tid * 4;
    UST* pl = ol + row * 1024 + tid * 4;
    const float4 gg = ((const float4*)g)[tid];
    const float4 bb = ((const float4*)b)[tid];
    float vv[4] = { v.x, v.y, v.z, v.w };
    float gv[4] = { gg.x, gg.y, gg.z, gg.w };
    float bv[4] = { bb.x, bb.y, bb.z, bb.w };
#pragma unroll
    for (int j = 0; j < 4; j++) {
        float f = (vv[j] - mean) * rstd * gv[j] + bv[j];
        UST hi = f2bf(f);
        ph[j] = hi;
        pl[j] = f2bf(f - bf2f(hi));
    }
}

// zero the conv-pad rows {b*4100 + 0,1,4098,4099} of LNh/LNl
__global__ void ln_pad_kernel(UST* __restrict__ oh, UST* __restrict__ ol)
{
    const int blk = blockIdx.x;          // 8 blocks
    const int b = blk >> 2, rsel = blk & 3;
    const long row = (long)b * 4100 + (rsel < 2 ? rsel : 4096 + rsel);
    const int tid = threadIdx.x;
    *(ushort4*)(oh + row * 1024 + tid * 4) = make_ushort4(0, 0, 0, 0);
    *(ushort4*)(ol + row * 1024 + tid * 4) = make_ushort4(0, 0, 0, 0);
}

// ---------------------------------------------------------------------------
// Coalesced transpose prep: dst[n*K+k] = src[k*N+n], bf16 hi (+lo).
// ---------------------------------------------------------------------------
__global__ void prep_t_kernel(const float* __restrict__ src, UST* __restrict__ dh,
                              UST* __restrict__ dl, int N, int K)
{
    __shared__ float tile[32][65];
    const int k0 = blockIdx.y * 32, n0 = blockIdx.x * 64;
    const int t = threadIdx.x;
    const int nn = t & 63, kk = t >> 6;
#pragma unroll
    for (int i = 0; i < 8; i++)
        tile[kk + i * 4][nn] = src[(long)(k0 + kk + i * 4) * N + n0 + nn];
    __syncthreads();
    const int kw = (t & 7) * 4;
#pragma unroll
    for (int pass = 0; pass < 2; pass++) {
        const int nw = (t >> 3) + pass * 32;
        UST hv[4], lv[4];
#pragma unroll
        for (int j = 0; j < 4; j++) {
            float v = tile[kw + j][nw];
            hv[j] = f2bf(v);
            lv[j] = f2bf(v - bf2f(hv[j]));
        }
        UST* bh = dh + (long)(n0 + nw) * K + k0 + kw;
        *(ushort4*)bh = make_ushort4(hv[0], hv[1], hv[2], hv[3]);
        if (dl) {
            UST* bl = dl + (long)(n0 + nw) * K + k0 + kw;
            *(ushort4*)bl = make_ushort4(lv[0], lv[1], lv[2], lv[3]);
        }
    }
}

// conv taps into concatenated B: dst[n*dstK + dstOff + k] = src[k*sr + n*sc]
__global__ void prep_w_kernel(const float* __restrict__ src, UST* __restrict__ dh,
                              UST* __restrict__ dl, int K, long sr, long sc,
                              int dstK, int dstOff, long total)
{
    long gid = (long)blockIdx.x * 256 + threadIdx.x;
    if (gid >= total) return;
    long n = gid / K, k = gid - n * K;
    float v = src[k * sr + n * sc];
    UST hi = f2bf(v);
    long di = n * dstK + dstOff + k;
    dh[di] = hi;
    if (dl) dl[di] = f2bf(v - bf2f(hi));
}

// ---------------------------------------------------------------------------
// GEMM: C[M,N] = A[M,K] * B^T[N,K]  (bf16, fp32 accum, MFMA 16x16x32)
// 128x128 tile, BK=32, 256 threads, global_load_lds(16B) staging.
// Counted-vmcnt double-buffer pipeline (R5), chain-broken MFMA sweeps (R7),
// XCD-aware bijective block swizzle (R7, non-gather only).
// GATHER mode (R8): blockIdx.y = linear M-tile over expert segments; the
// (expert, mtile) pair is derived on-device from cnt8; A rows come through
// perm (conv-padded row indices | rank<<15, into Ah=LNh); B/bias offset by
// expert id.
// EPI 3 (R9): plain store Cf[rank*8M + token*1024 + col] =
//             gelu(acc+bias_e)*combine[token][e]   (no atomics).
// SPLIT: A=Ah+Al, B=Bh+Bl -> AhBh + AhBl + AlBh (fp32-grade).
// A row stride KA; A k-offset = k0 + (k0>>10)*ASHIFT (conv seg trick).
// EPI 0: Cf = acc(+bias)(+resid) fp32. EPI 1: Cb = bf16(gelu(acc+bias)).
// EPI 2: scatter split bf16 into Sp = [Qh|Ql|Kh|Kl|Vth|Vtl] (attention prep).
// ---------------------------------------------------------------------------
template<int EPI, bool SPLIT, int ASHIFT, bool GATHER>
__global__ __launch_bounds__(256)
void gemm_bt_kernel(const UST* __restrict__ Ah, const UST* __restrict__ Al,
                    const UST* __restrict__ Bh, const UST* __restrict__ Bl,
                    const float* __restrict__ bias, const float* __restrict__ resid,
                    float* __restrict__ Cf, UST* __restrict__ Cb, UST* __restrict__ Sp,
                    int M, int N, int K, int KA, int rb, int radd,
                    const int* __restrict__ cnt8, const int* __restrict__ perm,
                    const float* __restrict__ combine)
{
    constexpr int ABUF = (SPLIT ? 2 : 1) * 4096;   // USTs per k-tile buffer
    __shared__ UST sA[2 * ABUF];
    __shared__ UST sB[2 * ABUF];
    const int tid = threadIdx.x;
    const int lane = tid & 63;
    const int wv = __builtin_amdgcn_readfirstlane(tid >> 6);
    const int wr = wv >> 1, wc = wv & 1;
    const int lm = lane & 15, lq = lane >> 4;

    int eidx = 0, cnt_e = 0, segbase = 0;
    long m0, n0;
    if constexpr (GATHER) {
        int mt = (int)blockIdx.y;
        int cnts[8];
#pragma unroll
        for (int e2 = 0; e2 < 8; e2++) cnts[e2] = cnt8[e2];
        int e2 = 0;
        for (;;) {
            const int te = (cnts[e2] + 127) >> 7;
            if (mt < te) break;
            mt -= te;
            if (++e2 == 8) return;           // spare block, uniform exit
        }
        eidx = e2; cnt_e = cnts[e2]; segbase = e2 << 13;
        m0 = (long)mt * 128;                 // segment-local row base
        n0 = (long)blockIdx.x * 128;
    } else {
        // XCD-aware bijective block swizzle (all GEMM grids have nwg % 8 == 0)
        const unsigned nwg = gridDim.x * gridDim.y;
        const unsigned orig = blockIdx.y * gridDim.x + blockIdx.x;
        const unsigned wg = (orig & 7u) * (nwg >> 3) + (orig >> 3);
        m0 = (long)(wg / gridDim.x) * 128;
        n0 = (long)(wg % gridDim.x) * 128;
    }

    const int lr = lane >> 2, lc = (lane & 3) * 8;
    const int rA0 = wv * 32 + lr, rA1 = wv * 32 + 16 + lr;
    const UST *gA0, *gA1;
    const UST *gA0l = nullptr, *gA1l = nullptr, *gB0l = nullptr, *gB1l = nullptr;
    const UST* Bhe = Bh;
    if constexpr (GATHER) {
        const int p0 = (int)m0 + rA0, p1 = (int)m0 + rA1;
        const int i0 = (p0 < cnt_e) ? (perm[segbase + p0] & 0x3FFF) : 0;  // row 0 = pad
        const int i1 = (p1 < cnt_e) ? (perm[segbase + p1] & 0x3FFF) : 0;
        gA0 = Ah + (long)i0 * KA + lc;
        gA1 = Ah + (long)i1 * KA + lc;
        Bhe = Bh + ((long)eidx << 20);       // expert weight block [1024x1024]
    } else {
        const long mtop = m0 >> 12;          // tiles never straddle 4096 rows
        gA0 = Ah + (m0 + rA0 + rb + (long)radd * mtop) * KA + lc;
        gA1 = Ah + (m0 + rA1 + rb + (long)radd * mtop) * KA + lc;
        if constexpr (SPLIT) {
            gA0l = Al + (m0 + rA0 + rb + (long)radd * mtop) * KA + lc;
            gA1l = Al + (m0 + rA1 + rb + (long)radd * mtop) * KA + lc;
        }
    }
    const UST* gB0 = Bhe + (n0 + rA0) * K + lc;
    const UST* gB1 = Bhe + (n0 + rA1) * K + lc;
    if constexpr (SPLIT) {
        gB0l = Bl + (n0 + rA0) * K + lc;
        gB1l = Bl + (n0 + rA1) * K + lc;
    }

    f32x4 acc[4][4] = {};
    s16x8 ah[4], bh[4], al[4], bl[4];

    // stage k-tile kk into buffer with per-wave bases dA/dB (wave-uniform)
    auto stage = [&](int kk, UST* dA, UST* dB) {
        const long aoff = ASHIFT ? (long)kk + (long)(kk >> 10) * ASHIFT : (long)kk;
        GLL(gA0 + aoff, dA); GLL(gA1 + aoff, dA + 512);
        GLL(gB0 + kk, dB); GLL(gB1 + kk, dB + 512);
        if (SPLIT) {
            GLL(gA0l + aoff, dA + 4096); GLL(gA1l + aoff, dA + 512 + 4096);
            GLL(gB0l + kk, dB + 4096); GLL(gB1l + kk, dB + 512 + 4096);
        }
    };
    // load all fragments of the staged tile at LDS bases cA/cB
    auto loads = [&](const UST* cA, const UST* cB) {
#pragma unroll
        for (int i = 0; i < 4; i++) {
            ah[i] = *(const s16x8*)&cA[(wr * 64 + i * 16 + lm) * 32 + lq * 8];
            bh[i] = *(const s16x8*)&cB[(wc * 64 + i * 16 + lm) * 32 + lq * 8];
        }
        if constexpr (SPLIT) {
#pragma unroll
            for (int i = 0; i < 4; i++) {
                al[i] = *(const s16x8*)&cA[4096 + (wr * 64 + i * 16 + lm) * 32 + lq * 8];
                bl[i] = *(const s16x8*)&cB[4096 + (wc * 64 + i * 16 + lm) * 32 + lq * 8];
            }
        }
    };
    // chain-broken MFMA cluster: three independent sweeps; each acc register
    // is touched once per sweep (16 issues apart) — no back-to-back dep chains.
    auto mfma_all = [&]() {
        __builtin_amdgcn_s_setprio(1);
#pragma unroll
        for (int i = 0; i < 4; i++)
#pragma unroll
            for (int j = 0; j < 4; j++)
                acc[i][j] = MFMA16(ah[i], bh[j], acc[i][j], 0, 0, 0);
        if constexpr (SPLIT) {
#pragma unroll
            for (int i = 0; i < 4; i++)
#pragma unroll
                for (int j = 0; j < 4; j++)
                    acc[i][j] = MFMA16(ah[i], bl[j], acc[i][j], 0, 0, 0);
#pragma unroll
            for (int i = 0; i < 4; i++)
#pragma unroll
                for (int j = 0; j < 4; j++)
                    acc[i][j] = MFMA16(al[i], bh[j], acc[i][j], 0, 0, 0);
        }
        __builtin_amdgcn_s_setprio(0);
    };
    auto vm_cur = [&]() {
        if constexpr (SPLIT) asm volatile("s_waitcnt vmcnt(8)" ::: "memory");
        else                 asm volatile("s_waitcnt vmcnt(4)" ::: "memory");
    };

    UST* wA0 = &sA[wv * 1024];               // wave-uniform LDS bases
    UST* wB0 = &sB[wv * 1024];
    UST* wA1 = &sA[ABUF + wv * 1024];
    UST* wB1 = &sB[ABUF + wv * 1024];

    stage(0, wA0, wB0);                      // tile 0 -> buf0
    stage(32, wA1, wB1);                     // tile 1 -> buf1
    for (int k0 = 0; k0 + 64 < K; k0 += 64) {
        vm_cur(); BARRIER();                 // tile k0/32 (buf0) fully in LDS
        loads(&sA[0], &sB[0]);
        LGKM0(); BARRIER();                  // all waves done reading buf0
        stage(k0 + 64, wA0, wB0);            // overlap with MFMA below
        mfma_all();
        vm_cur(); BARRIER();                 // tile k0/32+1 (buf1) in LDS
        loads(&sA[ABUF], &sB[ABUF]);
        LGKM0(); BARRIER();
        stage(k0 + 96, wA1, wB1);
        mfma_all();
    }
    // tail: tiles T-2 (buf0) and T-1 (buf1), no more staging
    vm_cur(); BARRIER();
    loads(&sA[0], &sB[0]);
    mfma_all();
    VM0(); BARRIER();
    loads(&sA[ABUF], &sB[ABUF]);
    mfma_all();

    // C/D layout (m89/m91-verified): col = lane&15, row = (lane>>4)*4 + reg
    const long SZ = 8388608L;
    const int colbase = (int)n0 + wc * 64;          // wave-uniform
    const int part = colbase >> 10;                 // EPI2: 0=Q,1=K,2=V
    const int hh = (colbase & 1023) >> 6;
    UST* H = (EPI == 2) ? (Sp + (long)part * 2 * SZ) : nullptr;
    UST* Lo = (EPI == 2) ? (H + SZ) : nullptr;
    const float* bias_e = bias;
    if constexpr (GATHER) bias_e = bias + (eidx << 10);
#pragma unroll
    for (int i = 0; i < 4; i++) {
#pragma unroll
        for (int j = 0; j < 4; j++) {
#pragma unroll
            for (int r = 0; r < 4; r++) {
                const long grow = m0 + wr * 64 + i * 16 + lq * 4 + r;
                const long gcol = n0 + wc * 64 + j * 16 + lm;
                float v = acc[i][j][r];
                if (bias) v += bias_e[gcol];
                if (EPI == 0) {
                    const long idx = grow * N + gcol;
                    if (resid) v += resid[idx];
                    Cf[idx] = v;
                } else if (EPI == 1) {
                    Cb[grow * N + gcol] = f2bf(gelu_f(v));
                } else if (EPI == 3) {
                    if (grow < cnt_e) {                 // grow is segment-local
                        const int pv = perm[segbase + grow];
                        const int prow = pv & 0x3FFF;
                        const int tok = prow - ((prow < 4100) ? 2 : 6);
                        const float wgt = combine[(long)tok * 8 + eidx];
                        // rank-split plain store: (token,rank,col) unique
                        Cf[(long)(pv >> 15) * SZ + (long)tok * 1024 + gcol] =
                            gelu_f(v) * wgt;
                    }
                } else {
                    const int d = j * 16 + lm;      // col within head
                    long idx;
                    if (part < 2) {
                        idx = ((long)hh * 8192 + grow) * 64 + d;
                    } else {
                        const int bb = (int)(grow >> 12), ww = (int)((grow >> 8) & 15),
                                  tt = (int)(grow & 255);
                        idx = ((long)((bb * 16 + ww) * 16 + hh)) * 16384 + (long)d * 256 + tt;
                    }
                    UST hi = f2bf(v);
                    H[idx] = hi;
                    Lo[idx] = f2bf(v - bf2f(hi));
                }
            }
        }
    }
}

// ---------------------------------------------------------------------------
// MFMA windowed attention (split-bf16, fp32-grade). Block = (b,win,head),
// 4 waves; wave owns 64 q-rows, iterates 8 k-chunks of 32 keys.
// S = QhKh+QhKl+QlKh (fp32 acc) -> P = exp(S/8) fp32 (scores bounded, no max)
// -> P split hi/lo through per-wave LDS (stride 40, 16B-aligned frag reads)
// -> O += PhVh+PhVl+PlVh.  l accumulated via cross-lane xor-reduce.
// Q frags live in registers whole kernel; K/V frags read from global (L2).
// ---------------------------------------------------------------------------
__global__ __launch_bounds__(256, 2)
void attn_mfma_kernel(const UST* __restrict__ Sp, UST* __restrict__ oh, UST* __restrict__ ol)
{
    __shared__ UST sPh[4 * 64 * 40];
    __shared__ UST sPl[4 * 64 * 40];
    const long SZ = 8388608L;
    const UST* Qh = Sp;
    const UST* Ql = Sp + SZ;
    const UST* Kh = Sp + 2 * SZ;
    const UST* Kl = Sp + 3 * SZ;
    const UST* Vth = Sp + 4 * SZ;
    const UST* Vtl = Sp + 5 * SZ;
    const int blk = blockIdx.x;
    const int h = blk & 15, w = (blk >> 4) & 15, b = blk >> 8;
    const long tok0 = (long)b * 4096 + w * 256;
    const int tid = threadIdx.x;
    const int lane = tid & 63;
    const int wv = tid >> 6;
    const int lm = lane & 15, lq = lane >> 4;

    // Q fragments (A-operand: m=lane&15, k=(lane>>4)*8+j), resident all kernel
    const long qrow0 = (long)h * 8192 + tok0 + wv * 64;
    s16x8 qhf[4][2], qlf[4][2];
#pragma unroll
    for (int mt = 0; mt < 4; mt++)
#pragma unroll
        for (int ks = 0; ks < 2; ks++) {
            const long o = (qrow0 + mt * 16 + lm) * 64 + ks * 32 + lq * 8;
            qhf[mt][ks] = *(const s16x8*)(Qh + o);
            qlf[mt][ks] = *(const s16x8*)(Ql + o);
        }
    const long krow0 = (long)h * 8192 + tok0;
    const long vbase = (long)blk * 16384;

    f32x4 Oacc[4][4] = {};
    float lsum[4][4] = {};
    UST* myPh = &sPh[wv * 2560];
    UST* myPl = &sPl[wv * 2560];

    for (int c = 0; c < 8; c++) {
        const int kt = c * 32;
        // ---- S = Q K^T (64q x 32k), split 3-product ----
        f32x4 S[4][2] = {};
#pragma unroll
        for (int nt = 0; nt < 2; nt++)
#pragma unroll
            for (int ks = 0; ks < 2; ks++) {
                const long o = (krow0 + kt + nt * 16 + lm) * 64 + ks * 32 + lq * 8;
                s16x8 khf = *(const s16x8*)(Kh + o);
                s16x8 klf = *(const s16x8*)(Kl + o);
#pragma unroll
                for (int mt = 0; mt < 4; mt++) {
                    S[mt][nt] = MFMA16(qhf[mt][ks], khf, S[mt][nt], 0, 0, 0);
                    S[mt][nt] = MFMA16(qhf[mt][ks], klf, S[mt][nt], 0, 0, 0);
                    S[mt][nt] = MFMA16(qlf[mt][ks], khf, S[mt][nt], 0, 0, 0);
                }
            }
        // ---- P = exp(S/8); l partial; write P split to LDS ----
#pragma unroll
        for (int mt = 0; mt < 4; mt++)
#pragma unroll
            for (int r = 0; r < 4; r++) {
                float p0 = __expf(S[mt][0][r] * 0.125f);
                float p1 = __expf(S[mt][1][r] * 0.125f);
                float part = p0 + p1;
                part += __shfl_xor(part, 1, 64);
                part += __shfl_xor(part, 2, 64);
                part += __shfl_xor(part, 4, 64);
                part += __shfl_xor(part, 8, 64);
                lsum[mt][r] += part;
                const int q = mt * 16 + lq * 4 + r;
                UST h0 = f2bf(p0), h1 = f2bf(p1);
                myPh[q * 40 + lm] = h0;
                myPh[q * 40 + 16 + lm] = h1;
                myPl[q * 40 + lm] = f2bf(p0 - bf2f(h0));
                myPl[q * 40 + 16 + lm] = f2bf(p1 - bf2f(h1));
            }
        // ---- O += P V (P from LDS A-frags, V^T from global B-frags) ----
#pragma unroll
        for (int mt = 0; mt < 4; mt++) {
            s16x8 phf = *(const s16x8*)(myPh + (mt * 16 + lm) * 40 + lq * 8);
            s16x8 plf = *(const s16x8*)(myPl + (mt * 16 + lm) * 40 + lq * 8);
#pragma unroll
            for (int dt = 0; dt < 4; dt++) {
                const long o = vbase + (dt * 16 + lm) * 256 + kt + lq * 8;
                s16x8 vhf = *(const s16x8*)(Vth + o);
                s16x8 vlf = *(const s16x8*)(Vtl + o);
                Oacc[mt][dt] = MFMA16(phf, vhf, Oacc[mt][dt], 0, 0, 0);
                Oacc[mt][dt] = MFMA16(phf, vlf, Oacc[mt][dt], 0, 0, 0);
                Oacc[mt][dt] = MFMA16(plf, vhf, Oacc[mt][dt], 0, 0, 0);
            }
        }
    }
    // ---- normalize + write split bf16 ----
#pragma unroll
    for (int mt = 0; mt < 4; mt++)
#pragma unroll
        for (int r = 0; r < 4; r++) {
            const float inv = 1.0f / lsum[mt][r];
            const long tok = tok0 + wv * 64 + mt * 16 + lq * 4 + r;
            UST* po = oh + tok * 1024 + h * 64;
            UST* plo = ol + tok * 1024 + h * 64;
#pragma unroll
            for (int dt = 0; dt < 4; dt++) {
                float f = Oacc[mt][dt][r] * inv;
                UST hv = f2bf(f);
                po[dt * 16 + lm] = hv;
                plo[dt * 16 + lm] = f2bf(f - bf2f(hv));
            }
        }
}

// ---------------------------------------------------------------------------
// Gate: logits (hi+lo fp32-grade), softmax, entropy, top-2 -> combine weights
// + per-expert token lists (cnt8 histogram, perm = padded row | rank<<15).
// ---------------------------------------------------------------------------
__global__ void gate_kernel(const UST* __restrict__ lnh, const UST* __restrict__ lnl,
                            const float* __restrict__ gw, const float* __restrict__ gb,
                            float* __restrict__ combine, float* __restrict__ ent_acc,
                            int* __restrict__ cnt8, int* __restrict__ perm)
{
    const int tid = threadIdx.x;
    const int t = blockIdx.x * 4 + (tid >> 6);
    const int lane = tid & 63;
    const long row = (long)t + 2 + 4 * (t >> 12);
    const UST* ph = lnh + row * 1024;
    const UST* pl = lnl + row * 1024;
    float acc[8] = { 0, 0, 0, 0, 0, 0, 0, 0 };
    for (int c = 0; c < 16; c++) {
        int d = c * 64 + lane;
        float xv = bf2f(ph[d]) + bf2f(pl[d]);
        const float* wr = gw + (long)d * 8;
#pragma unroll
        for (int e = 0; e < 8; e++) acc[e] += xv * wr[e];
    }
#pragma unroll
    for (int e = 0; e < 8; e++)
        for (int o = 32; o > 0; o >>= 1) acc[e] += __shfl_xor(acc[e], o, 64);
    if (lane == 0) {
        float lg[8], p[8];
        float mx = -1e30f;
        for (int e = 0; e < 8; e++) { lg[e] = acc[e] + gb[e]; mx = fmaxf(mx, lg[e]); }
        float sum = 0;
        for (int e = 0; e < 8; e++) { p[e] = expf(lg[e] - mx); sum += p[e]; }
        float inv = 1.0f / sum;
        float ent = 0;
        for (int e = 0; e < 8; e++) { p[e] *= inv; ent -= p[e] * logf(p[e] + 1e-10f); }
        int i1 = 0; float v1 = -1e30f;
        for (int e = 0; e < 8; e++) if (p[e] > v1) { v1 = p[e]; i1 = e; }
        int i2 = 0; float v2 = -1e30f;
        for (int e = 0; e < 8; e++) if (e != i1 && p[e] > v2) { v2 = p[e]; i2 = e; }
        float inv2 = 1.0f / (v1 + v2);
        float cw[8] = { 0, 0, 0, 0, 0, 0, 0, 0 };
        cw[i1] = v1 * inv2; cw[i2] = v2 * inv2;
        float* co = combine + (long)t * 8;
        for (int e = 0; e < 8; e++) co[e] = cw[e];
        const int s1 = atomicAdd(&cnt8[i1], 1);
        perm[(i1 << 13) + s1] = (int)row;                // rank 0 (top-1)
        const int s2 = atomicAdd(&cnt8[i2], 1);
        perm[(i2 << 13) + s2] = (int)row | 32768;        // rank 1 (top-2)
        atomicAdd(ent_acc, ent);
    }
}

// out += buf0 + buf1 (rank-split MoE partials), float4-vectorized
__global__ void moe_add_kernel(const float* __restrict__ b0, const float* __restrict__ b1,
                               float* __restrict__ out)
{
    const long gid = ((long)blockIdx.x * 256 + threadIdx.x) * 4;
    const float4 v0 = *(const float4*)(b0 + gid);
    const float4 v1 = *(const float4*)(b1 + gid);
    float4 o = *(float4*)(out + gid);
    o.x += v0.x + v1.x; o.y += v0.y + v1.y;
    o.z += v0.z + v1.z; o.w += v0.w + v1.w;
    *(float4*)(out + gid) = o;
}

__global__ void f32_to_bf16_kernel(const float* __restrict__ in, UST* __restrict__ out)
{
    long gid = ((long)blockIdx.x * 256 + threadIdx.x) * 4;
    float4 v = *(const float4*)(in + gid);
    out[gid] = f2bf(v.x); out[gid + 1] = f2bf(v.y);
    out[gid + 2] = f2bf(v.z); out[gid + 3] = f2bf(v.w);
}

__global__ void ent_final_kernel(const float* __restrict__ acc, float* __restrict__ out)
{
    out[0] = 0.1f * acc[0] * (1.0f / 8192.0f);
}

// ===========================================================================
extern "C" void kernel_launch(void* const* d_in, const int* in_sizes, int n_in,
                              void* d_out_, int out_size, void* d_ws, size_t ws_size,
                              hipStream_t stream)
{
    const float* x      = (const float*)d_in[0];
    const float* ln1_g  = (const float*)d_in[1];
    const float* ln1_b  = (const float*)d_in[2];
    const float* qkv_w  = (const float*)d_in[3];
    const float* qkv_b  = (const float*)d_in[4];
    const float* ao_w   = (const float*)d_in[5];
    const float* ao_b   = (const float*)d_in[6];
    const float* ln2_g  = (const float*)d_in[7];
    const float* ln2_b  = (const float*)d_in[8];
    const float* conv_w = (const float*)d_in[9];
    const float* conv_b = (const float*)d_in[10];
    const float* ln3_g  = (const float*)d_in[11];
    const float* ln3_b  = (const float*)d_in[12];
    const float* gate_w = (const float*)d_in[13];
    const float* gate_b = (const float*)d_in[14];
    const float* exp_w  = (const float*)d_in[15];
    const float* exp_b  = (const float*)d_in[16];
    const float* ff_w1  = (const float*)d_in[17];
    const float* ff_b1  = (const float*)d_in[18];
    const float* ff_w2  = (const float*)d_in[19];
    const float* ff_b2  = (const float*)d_in[20];
    float* out = (float*)d_out_;

    char* ws = (char*)d_ws;
    size_t off = 0;
    auto alloc = [&](size_t bytes) -> char* {
        char* p = ws + off;
        off += (bytes + 255) & ~(size_t)255;
        return p;
    };
    UST* qkvWh = (UST*)alloc(3072 * 1024 * 2);
    UST* qkvWl = (UST*)alloc(3072 * 1024 * 2);
    UST* aoWh  = (UST*)alloc(1024 * 1024 * 2);
    UST* aoWl  = (UST*)alloc(1024 * 1024 * 2);
    UST* convCh = (UST*)alloc(1024L * 3072 * 2);   // [n=1024][k=3072] concat taps
    UST* convCl = (UST*)alloc(1024L * 3072 * 2);
    UST* expW  = (UST*)alloc(8192L * 1024 * 2);
    UST* ff1W  = (UST*)alloc(4096L * 1024 * 2);
    UST* ff2W  = (UST*)alloc(4096L * 1024 * 2);
    const size_t LN_BYTES = 8200L * 1024 * 2;
    UST* LNh = (UST*)alloc(LN_BYTES);
    UST* LNl = (UST*)alloc(LN_BYTES);
    float* combine = (float*)alloc(8192 * 8 * 4);
    float* entacc  = (float*)alloc(256);
    int*   cnt8    = (int*)alloc(256);
    int*   perm    = (int*)alloc(8 * 8192 * 4);
    char*  BIG = alloc(8192L * 3072 * 4);     // Sp during attn; moebuf; h1 later
    UST* OH = (UST*)alloc(8192L * 1024 * 2);  // attn out hi; later x3 bf16
    UST* OL = (UST*)alloc(8192L * 1024 * 2);
    if (off > ws_size) return;  // ws too small -> deliberate clean fail

    UST* Sp   = (UST*)BIG;      // [Qh|Ql|Kh|Kl|Vth|Vtl]
    float* moebuf = (float*)BIG; // [2][8192][1024] fp32 rank-split partials
    UST* h1   = (UST*)BIG;
    UST* x3h  = OH;

    // ---- weight prep (every call; ws is re-poisoned) ----
    auto nb = [](long n) { return (unsigned)((n + 255) / 256); };
    prep_t_kernel<<<dim3(48, 32), 256, 0, stream>>>(qkv_w, qkvWh, qkvWl, 3072, 1024);
    prep_t_kernel<<<dim3(16, 32), 256, 0, stream>>>(ao_w, aoWh, aoWl, 1024, 1024);
    for (int k = 0; k < 3; k++)
        prep_w_kernel<<<nb(1024L * 1024), 256, 0, stream>>>(conv_w + k, convCh, convCl,
                                                            1024, 3, 3072, 3072, k * 1024, 1024L * 1024);
    for (int e = 0; e < 8; e++)
        prep_t_kernel<<<dim3(16, 32), 256, 0, stream>>>(exp_w + (long)e * 1048576, expW + (long)e * 1048576,
                                                        nullptr, 1024, 1024);
    prep_t_kernel<<<dim3(64, 32), 256, 0, stream>>>(ff_w1, ff1W, nullptr, 4096, 1024);
    prep_t_kernel<<<dim3(16, 128), 256, 0, stream>>>(ff_w2, ff2W, nullptr, 1024, 4096);

    ln_pad_kernel<<<8, 256, 0, stream>>>(LNh, LNl);
    hipMemsetAsync(entacc, 0, 4, stream);
    hipMemsetAsync(cnt8, 0, 32, stream);

    // ---- attention block ----
    ln_split_kernel<<<8192, 256, 0, stream>>>(x, ln1_g, ln1_b, LNh, LNl);
    gemm_bt_kernel<2, true, 0, false><<<dim3(24, 64), 256, 0, stream>>>(
        LNh, LNl, qkvWh, qkvWl, qkv_b, nullptr, nullptr, nullptr, Sp,
        8192, 3072, 1024, 1024, 2, 4, nullptr, nullptr, nullptr);
    attn_mfma_kernel<<<512, 256, 0, stream>>>(Sp, OH, OL);
    gemm_bt_kernel<0, true, 0, false><<<dim3(8, 64), 256, 0, stream>>>(
        OH, OL, aoWh, aoWl, ao_b, x, out, nullptr, nullptr,
        8192, 1024, 1024, 1024, 0, 0, nullptr, nullptr, nullptr);
    // ---- dilated conv block: ONE fused GEMM, K=3072 (3 shifted segments) ----
    ln_split_kernel<<<8192, 256, 0, stream>>>(out, ln2_g, ln2_b, LNh, LNl);
    gemm_bt_kernel<0, true, 1024, false><<<dim3(8, 64), 256, 0, stream>>>(
        LNh, LNl, convCh, convCl, conv_b, out, out, nullptr, nullptr,
        8192, 1024, 3072, 1024, 0, 4, nullptr, nullptr, nullptr);
    // ---- MoE: gate -> sparse gathered expert GEMM (top-2 only, exact) ----
    ln_split_kernel<<<8192, 256, 0, stream>>>(out, ln3_g, ln3_b, LNh, LNl);
    gate_kernel<<<2048, 256, 0, stream>>>(LNh, LNl, gate_w, gate_b, combine, entacc, cnt8, perm);
    ent_final_kernel<<<1, 1, 0, stream>>>(entacc, out + 8388608);
    gemm_bt_kernel<3, false, 0, true><<<dim3(8, 136), 256, 0, stream>>>(
        LNh, nullptr, expW, nullptr, exp_b, nullptr, moebuf, nullptr, nullptr,
        8192, 1024, 1024, 1024, 0, 0, cnt8, perm, combine);
    moe_add_kernel<<<8192, 256, 0, stream>>>(moebuf, moebuf + 8388608, out);
    // ---- FFN ----
    f32_to_bf16_kernel<<<8192, 256, 0, stream>>>(out, x3h);
    gemm_bt_kernel<1, false, 0, false><<<dim3(32, 64), 256, 0, stream>>>(
        x3h, nullptr, ff1W, nullptr, ff_b1, nullptr, nullptr, h1, nullptr,
        8192, 4096, 1024, 1024, 0, 0, nullptr, nullptr, nullptr);
    gemm_bt_kernel<0, false, 0, false><<<dim3(8, 64), 256, 0, stream>>>(
        h1, nullptr, ff2W, nullptr, ff_b2, out, out, nullptr, nullptr,
        8192, 1024, 4096, 4096, 0, 0, nullptr, nullptr, nullptr);
}

// Round 7
// 1220.881 us; speedup vs baseline: 1.2577x; 1.2577x over previous
//
#include <hip/hip_runtime.h>
#include <hip/hip_bf16.h>
#include <math.h>

// ============================================================================
// ImprovedTransformerBlock on MI355X.  R10 = R9 with MoE routing made
// ATOMIC-FREE (R9's gate_kernel burned 258us on 24.6K same-cache-line
// value-returning atomics to cnt8/ent_acc — measured ~0% on every pipe):
//   gate_kernel  -> combine[8], entbuf[t], tokexp[t]=i1|(i2<<4).  NO atomics.
//   moe_sort     -> 8 blocks (1/expert) compact perm via ballot+prefix scan,
//                   one cnt8 store per block.  Bucket order arbitrary (exact).
//   ent_final    -> single-block tree reduce of entbuf.
// Gather GEMM (rank-split plain stores) + moe_add unchanged from R9.
// GEMM core unchanged from R7 (chain-broken MFMA, XCD swizzle, counted-vmcnt
// double-buffer, 128x128, global_load_lds staging).
// ============================================================================

typedef unsigned short UST;
typedef unsigned int uint32;
typedef float f32x4 __attribute__((ext_vector_type(4)));
using s16x8 = __attribute__((ext_vector_type(8))) short;   // 8 bf16 = 4 VGPRs

#define DEV __device__ __forceinline__
#define MFMA16 __builtin_amdgcn_mfma_f32_16x16x32_bf16

// async global->LDS, 16 bytes/lane; lds dst is wave-uniform base + lane*16
#define GLL(g, l) __builtin_amdgcn_global_load_lds( \
    (const __attribute__((address_space(1))) unsigned int*)(g), \
    (__attribute__((address_space(3))) unsigned int*)(l), 16, 0, 0)

// raw sync primitives (counted vmcnt pipeline) — asm with memory clobber so
// compiler-generated ds_read/GLL cannot migrate across them.
#define BARRIER()  asm volatile("s_barrier" ::: "memory")
#define LGKM0()    asm volatile("s_waitcnt lgkmcnt(0)" ::: "memory")
#define VM0()      asm volatile("s_waitcnt vmcnt(0)" ::: "memory")

DEV UST f2bf(float f) {                       // round-to-nearest-even fp32->bf16
    uint32 u = __float_as_uint(f);
    u += 0x7FFFu + ((u >> 16) & 1u);
    return (UST)(u >> 16);
}
DEV float bf2f(UST h) { return __uint_as_float(((uint32)h) << 16); }
DEV float gelu_f(float x) { return 0.5f * x * (1.0f + erff(x * 0.7071067811865475f)); }

// ---------------------------------------------------------------------------
// LayerNorm -> split bf16 (hi/lo), conv-padded row layout: row(t)=t+2+4*(t>>12)
// ---------------------------------------------------------------------------
__global__ void ln_split_kernel(const float* __restrict__ x,
                                const float* __restrict__ g, const float* __restrict__ b,
                                UST* __restrict__ oh, UST* __restrict__ ol)
{
    const int t = blockIdx.x;
    const int tid = threadIdx.x;
    const float4 v = ((const float4*)(x + (long)t * 1024))[tid];
    float s = v.x + v.y + v.z + v.w;
    float q = v.x * v.x + v.y * v.y + v.z * v.z + v.w * v.w;
    for (int o = 32; o > 0; o >>= 1) { s += __shfl_xor(s, o, 64); q += __shfl_xor(q, o, 64); }
    __shared__ float ss[4], sq[4];
    const int wave = tid >> 6, lane = tid & 63;
    if (lane == 0) { ss[wave] = s; sq[wave] = q; }
    __syncthreads();
    s = ss[0] + ss[1] + ss[2] + ss[3];
    q = sq[0] + sq[1] + sq[2] + sq[3];
    const float mean = s * (1.0f / 1024.0f);
    const float var = q * (1.0f / 1024.0f) - mean * mean;
    const float rstd = 1.0f / sqrtf(var + 1e-5f);
    const long row = (long)t + 2 + 4 * (t >> 12);
    UST* ph = oh + row * 1024 + tid * 4;
    UST* pl = ol + row * 1024 + tid * 4;
    const float4 gg = ((const float4*)g)[tid];
    const float4 bb = ((const float4*)b)[tid];
    float vv[4] = { v.x, v.y, v.z, v.w };
    float gv[4] = { gg.x, gg.y, gg.z, gg.w };
    float bv[4] = { bb.x, bb.y, bb.z, bb.w };
#pragma unroll
    for (int j = 0; j < 4; j++) {
        float f = (vv[j] - mean) * rstd * gv[j] + bv[j];
        UST hi = f2bf(f);
        ph[j] = hi;
        pl[j] = f2bf(f - bf2f(hi));
    }
}

// zero the conv-pad rows {b*4100 + 0,1,4098,4099} of LNh/LNl
__global__ void ln_pad_kernel(UST* __restrict__ oh, UST* __restrict__ ol)
{
    const int blk = blockIdx.x;          // 8 blocks
    const int b = blk >> 2, rsel = blk & 3;
    const long row = (long)b * 4100 + (rsel < 2 ? rsel : 4096 + rsel);
    const int tid = threadIdx.x;
    *(ushort4*)(oh + row * 1024 + tid * 4) = make_ushort4(0, 0, 0, 0);
    *(ushort4*)(ol + row * 1024 + tid * 4) = make_ushort4(0, 0, 0, 0);
}

// ---------------------------------------------------------------------------
// Coalesced transpose prep: dst[n*K+k] = src[k*N+n], bf16 hi (+lo).
// ---------------------------------------------------------------------------
__global__ void prep_t_kernel(const float* __restrict__ src, UST* __restrict__ dh,
                              UST* __restrict__ dl, int N, int K)
{
    __shared__ float tile[32][65];
    const int k0 = blockIdx.y * 32, n0 = blockIdx.x * 64;
    const int t = threadIdx.x;
    const int nn = t & 63, kk = t >> 6;
#pragma unroll
    for (int i = 0; i < 8; i++)
        tile[kk + i * 4][nn] = src[(long)(k0 + kk + i * 4) * N + n0 + nn];
    __syncthreads();
    const int kw = (t & 7) * 4;
#pragma unroll
    for (int pass = 0; pass < 2; pass++) {
        const int nw = (t >> 3) + pass * 32;
        UST hv[4], lv[4];
#pragma unroll
        for (int j = 0; j < 4; j++) {
            float v = tile[kw + j][nw];
            hv[j] = f2bf(v);
            lv[j] = f2bf(v - bf2f(hv[j]));
        }
        UST* bh = dh + (long)(n0 + nw) * K + k0 + kw;
        *(ushort4*)bh = make_ushort4(hv[0], hv[1], hv[2], hv[3]);
        if (dl) {
            UST* bl = dl + (long)(n0 + nw) * K + k0 + kw;
            *(ushort4*)bl = make_ushort4(lv[0], lv[1], lv[2], lv[3]);
        }
    }
}

// conv taps into concatenated B: dst[n*dstK + dstOff + k] = src[k*sr + n*sc]
__global__ void prep_w_kernel(const float* __restrict__ src, UST* __restrict__ dh,
                              UST* __restrict__ dl, int K, long sr, long sc,
                              int dstK, int dstOff, long total)
{
    long gid = (long)blockIdx.x * 256 + threadIdx.x;
    if (gid >= total) return;
    long n = gid / K, k = gid - n * K;
    float v = src[k * sr + n * sc];
    UST hi = f2bf(v);
    long di = n * dstK + dstOff + k;
    dh[di] = hi;
    if (dl) dl[di] = f2bf(v - bf2f(hi));
}

// ---------------------------------------------------------------------------
// GEMM: C[M,N] = A[M,K] * B^T[N,K]  (bf16, fp32 accum, MFMA 16x16x32)
// 128x128 tile, BK=32, 256 threads, global_load_lds(16B) staging.
// Counted-vmcnt double-buffer pipeline (R5), chain-broken MFMA sweeps (R7),
// XCD-aware bijective block swizzle (R7, non-gather only).
// GATHER mode: blockIdx.y = linear M-tile over expert segments; (expert,
// mtile) derived on-device from cnt8; A rows via perm (padded row | rank<<15
// into Ah=LNh); B/bias offset by expert id.
// EPI 3: plain store Cf[rank*8M + token*1024 + col] = gelu(acc+bias_e)*wgt.
// SPLIT: A=Ah+Al, B=Bh+Bl -> AhBh + AhBl + AlBh (fp32-grade).
// A row stride KA; A k-offset = k0 + (k0>>10)*ASHIFT (conv seg trick).
// EPI 0: Cf = acc(+bias)(+resid) fp32. EPI 1: Cb = bf16(gelu(acc+bias)).
// EPI 2: scatter split bf16 into Sp = [Qh|Ql|Kh|Kl|Vth|Vtl] (attention prep).
// ---------------------------------------------------------------------------
template<int EPI, bool SPLIT, int ASHIFT, bool GATHER>
__global__ __launch_bounds__(256)
void gemm_bt_kernel(const UST* __restrict__ Ah, const UST* __restrict__ Al,
                    const UST* __restrict__ Bh, const UST* __restrict__ Bl,
                    const float* __restrict__ bias, const float* __restrict__ resid,
                    float* __restrict__ Cf, UST* __restrict__ Cb, UST* __restrict__ Sp,
                    int M, int N, int K, int KA, int rb, int radd,
                    const int* __restrict__ cnt8, const int* __restrict__ perm,
                    const float* __restrict__ combine)
{
    constexpr int ABUF = (SPLIT ? 2 : 1) * 4096;   // USTs per k-tile buffer
    __shared__ UST sA[2 * ABUF];
    __shared__ UST sB[2 * ABUF];
    const int tid = threadIdx.x;
    const int lane = tid & 63;
    const int wv = __builtin_amdgcn_readfirstlane(tid >> 6);
    const int wr = wv >> 1, wc = wv & 1;
    const int lm = lane & 15, lq = lane >> 4;

    int eidx = 0, cnt_e = 0, segbase = 0;
    long m0, n0;
    if constexpr (GATHER) {
        int mt = (int)blockIdx.y;
        int cnts[8];
#pragma unroll
        for (int e2 = 0; e2 < 8; e2++) cnts[e2] = cnt8[e2];
        int e2 = 0;
        for (;;) {
            const int te = (cnts[e2] + 127) >> 7;
            if (mt < te) break;
            mt -= te;
            if (++e2 == 8) return;           // spare block, uniform exit
        }
        eidx = e2; cnt_e = cnts[e2]; segbase = e2 << 13;
        m0 = (long)mt * 128;                 // segment-local row base
        n0 = (long)blockIdx.x * 128;
    } else {
        // XCD-aware bijective block swizzle (all GEMM grids have nwg % 8 == 0)
        const unsigned nwg = gridDim.x * gridDim.y;
        const unsigned orig = blockIdx.y * gridDim.x + blockIdx.x;
        const unsigned wg = (orig & 7u) * (nwg >> 3) + (orig >> 3);
        m0 = (long)(wg / gridDim.x) * 128;
        n0 = (long)(wg % gridDim.x) * 128;
    }

    const int lr = lane >> 2, lc = (lane & 3) * 8;
    const int rA0 = wv * 32 + lr, rA1 = wv * 32 + 16 + lr;
    const UST *gA0, *gA1;
    const UST *gA0l = nullptr, *gA1l = nullptr, *gB0l = nullptr, *gB1l = nullptr;
    const UST* Bhe = Bh;
    if constexpr (GATHER) {
        const int p0 = (int)m0 + rA0, p1 = (int)m0 + rA1;
        const int i0 = (p0 < cnt_e) ? (perm[segbase + p0] & 0x3FFF) : 0;  // row 0 = pad
        const int i1 = (p1 < cnt_e) ? (perm[segbase + p1] & 0x3FFF) : 0;
        gA0 = Ah + (long)i0 * KA + lc;
        gA1 = Ah + (long)i1 * KA + lc;
        Bhe = Bh + ((long)eidx << 20);       // expert weight block [1024x1024]
    } else {
        const long mtop = m0 >> 12;          // tiles never straddle 4096 rows
        gA0 = Ah + (m0 + rA0 + rb + (long)radd * mtop) * KA + lc;
        gA1 = Ah + (m0 + rA1 + rb + (long)radd * mtop) * KA + lc;
        if constexpr (SPLIT) {
            gA0l = Al + (m0 + rA0 + rb + (long)radd * mtop) * KA + lc;
            gA1l = Al + (m0 + rA1 + rb + (long)radd * mtop) * KA + lc;
        }
    }
    const UST* gB0 = Bhe + (n0 + rA0) * K + lc;
    const UST* gB1 = Bhe + (n0 + rA1) * K + lc;
    if constexpr (SPLIT) {
        gB0l = Bl + (n0 + rA0) * K + lc;
        gB1l = Bl + (n0 + rA1) * K + lc;
    }

    f32x4 acc[4][4] = {};
    s16x8 ah[4], bh[4], al[4], bl[4];

    // stage k-tile kk into buffer with per-wave bases dA/dB (wave-uniform)
    auto stage = [&](int kk, UST* dA, UST* dB) {
        const long aoff = ASHIFT ? (long)kk + (long)(kk >> 10) * ASHIFT : (long)kk;
        GLL(gA0 + aoff, dA); GLL(gA1 + aoff, dA + 512);
        GLL(gB0 + kk, dB); GLL(gB1 + kk, dB + 512);
        if (SPLIT) {
            GLL(gA0l + aoff, dA + 4096); GLL(gA1l + aoff, dA + 512 + 4096);
            GLL(gB0l + kk, dB + 4096); GLL(gB1l + kk, dB + 512 + 4096);
        }
    };
    // load all fragments of the staged tile at LDS bases cA/cB
    auto loads = [&](const UST* cA, const UST* cB) {
#pragma unroll
        for (int i = 0; i < 4; i++) {
            ah[i] = *(const s16x8*)&cA[(wr * 64 + i * 16 + lm) * 32 + lq * 8];
            bh[i] = *(const s16x8*)&cB[(wc * 64 + i * 16 + lm) * 32 + lq * 8];
        }
        if constexpr (SPLIT) {
#pragma unroll
            for (int i = 0; i < 4; i++) {
                al[i] = *(const s16x8*)&cA[4096 + (wr * 64 + i * 16 + lm) * 32 + lq * 8];
                bl[i] = *(const s16x8*)&cB[4096 + (wc * 64 + i * 16 + lm) * 32 + lq * 8];
            }
        }
    };
    // chain-broken MFMA cluster: three independent sweeps; each acc register
    // is touched once per sweep (16 issues apart) — no back-to-back dep chains.
    auto mfma_all = [&]() {
        __builtin_amdgcn_s_setprio(1);
#pragma unroll
        for (int i = 0; i < 4; i++)
#pragma unroll
            for (int j = 0; j < 4; j++)
                acc[i][j] = MFMA16(ah[i], bh[j], acc[i][j], 0, 0, 0);
        if constexpr (SPLIT) {
#pragma unroll
            for (int i = 0; i < 4; i++)
#pragma unroll
                for (int j = 0; j < 4; j++)
                    acc[i][j] = MFMA16(ah[i], bl[j], acc[i][j], 0, 0, 0);
#pragma unroll
            for (int i = 0; i < 4; i++)
#pragma unroll
                for (int j = 0; j < 4; j++)
                    acc[i][j] = MFMA16(al[i], bh[j], acc[i][j], 0, 0, 0);
        }
        __builtin_amdgcn_s_setprio(0);
    };
    auto vm_cur = [&]() {
        if constexpr (SPLIT) asm volatile("s_waitcnt vmcnt(8)" ::: "memory");
        else                 asm volatile("s_waitcnt vmcnt(4)" ::: "memory");
    };

    UST* wA0 = &sA[wv * 1024];               // wave-uniform LDS bases
    UST* wB0 = &sB[wv * 1024];
    UST* wA1 = &sA[ABUF + wv * 1024];
    UST* wB1 = &sB[ABUF + wv * 1024];

    stage(0, wA0, wB0);                      // tile 0 -> buf0
    stage(32, wA1, wB1);                     // tile 1 -> buf1
    for (int k0 = 0; k0 + 64 < K; k0 += 64) {
        vm_cur(); BARRIER();                 // tile k0/32 (buf0) fully in LDS
        loads(&sA[0], &sB[0]);
        LGKM0(); BARRIER();                  // all waves done reading buf0
        stage(k0 + 64, wA0, wB0);            // overlap with MFMA below
        mfma_all();
        vm_cur(); BARRIER();                 // tile k0/32+1 (buf1) in LDS
        loads(&sA[ABUF], &sB[ABUF]);
        LGKM0(); BARRIER();
        stage(k0 + 96, wA1, wB1);
        mfma_all();
    }
    // tail: tiles T-2 (buf0) and T-1 (buf1), no more staging
    vm_cur(); BARRIER();
    loads(&sA[0], &sB[0]);
    mfma_all();
    VM0(); BARRIER();
    loads(&sA[ABUF], &sB[ABUF]);
    mfma_all();

    // C/D layout (m89/m91-verified): col = lane&15, row = (lane>>4)*4 + reg
    const long SZ = 8388608L;
    const int colbase = (int)n0 + wc * 64;          // wave-uniform
    const int part = colbase >> 10;                 // EPI2: 0=Q,1=K,2=V
    const int hh = (colbase & 1023) >> 6;
    UST* H = (EPI == 2) ? (Sp + (long)part * 2 * SZ) : nullptr;
    UST* Lo = (EPI == 2) ? (H + SZ) : nullptr;
    const float* bias_e = bias;
    if constexpr (GATHER) bias_e = bias + (eidx << 10);
#pragma unroll
    for (int i = 0; i < 4; i++) {
#pragma unroll
        for (int j = 0; j < 4; j++) {
#pragma unroll
            for (int r = 0; r < 4; r++) {
                const long grow = m0 + wr * 64 + i * 16 + lq * 4 + r;
                const long gcol = n0 + wc * 64 + j * 16 + lm;
                float v = acc[i][j][r];
                if (bias) v += bias_e[gcol];
                if (EPI == 0) {
                    const long idx = grow * N + gcol;
                    if (resid) v += resid[idx];
                    Cf[idx] = v;
                } else if (EPI == 1) {
                    Cb[grow * N + gcol] = f2bf(gelu_f(v));
                } else if (EPI == 3) {
                    if (grow < cnt_e) {                 // grow is segment-local
                        const int pv = perm[segbase + grow];
                        const int prow = pv & 0x3FFF;
                        const int tok = prow - ((prow < 4100) ? 2 : 6);
                        const float wgt = combine[(long)tok * 8 + eidx];
                        // rank-split plain store: (token,rank,col) unique
                        Cf[(long)(pv >> 15) * SZ + (long)tok * 1024 + gcol] =
                            gelu_f(v) * wgt;
                    }
                } else {
                    const int d = j * 16 + lm;      // col within head
                    long idx;
                    if (part < 2) {
                        idx = ((long)hh * 8192 + grow) * 64 + d;
                    } else {
                        const int bb = (int)(grow >> 12), ww = (int)((grow >> 8) & 15),
                                  tt = (int)(grow & 255);
                        idx = ((long)((bb * 16 + ww) * 16 + hh)) * 16384 + (long)d * 256 + tt;
                    }
                    UST hi = f2bf(v);
                    H[idx] = hi;
                    Lo[idx] = f2bf(v - bf2f(hi));
                }
            }
        }
    }
}

// ---------------------------------------------------------------------------
// MFMA windowed attention (split-bf16, fp32-grade). Block = (b,win,head),
// 4 waves; wave owns 64 q-rows, iterates 8 k-chunks of 32 keys.
// S = QhKh+QhKl+QlKh (fp32 acc) -> P = exp(S/8) fp32 (scores bounded, no max)
// -> P split hi/lo through per-wave LDS (stride 40, 16B-aligned frag reads)
// -> O += PhVh+PhVl+PlVh.  l accumulated via cross-lane xor-reduce.
// Q frags live in registers whole kernel; K/V frags read from global (L2).
// ---------------------------------------------------------------------------
__global__ __launch_bounds__(256, 2)
void attn_mfma_kernel(const UST* __restrict__ Sp, UST* __restrict__ oh, UST* __restrict__ ol)
{
    __shared__ UST sPh[4 * 64 * 40];
    __shared__ UST sPl[4 * 64 * 40];
    const long SZ = 8388608L;
    const UST* Qh = Sp;
    const UST* Ql = Sp + SZ;
    const UST* Kh = Sp + 2 * SZ;
    const UST* Kl = Sp + 3 * SZ;
    const UST* Vth = Sp + 4 * SZ;
    const UST* Vtl = Sp + 5 * SZ;
    const int blk = blockIdx.x;
    const int h = blk & 15, w = (blk >> 4) & 15, b = blk >> 8;
    const long tok0 = (long)b * 4096 + w * 256;
    const int tid = threadIdx.x;
    const int lane = tid & 63;
    const int wv = tid >> 6;
    const int lm = lane & 15, lq = lane >> 4;

    // Q fragments (A-operand: m=lane&15, k=(lane>>4)*8+j), resident all kernel
    const long qrow0 = (long)h * 8192 + tok0 + wv * 64;
    s16x8 qhf[4][2], qlf[4][2];
#pragma unroll
    for (int mt = 0; mt < 4; mt++)
#pragma unroll
        for (int ks = 0; ks < 2; ks++) {
            const long o = (qrow0 + mt * 16 + lm) * 64 + ks * 32 + lq * 8;
            qhf[mt][ks] = *(const s16x8*)(Qh + o);
            qlf[mt][ks] = *(const s16x8*)(Ql + o);
        }
    const long krow0 = (long)h * 8192 + tok0;
    const long vbase = (long)blk * 16384;

    f32x4 Oacc[4][4] = {};
    float lsum[4][4] = {};
    UST* myPh = &sPh[wv * 2560];
    UST* myPl = &sPl[wv * 2560];

    for (int c = 0; c < 8; c++) {
        const int kt = c * 32;
        // ---- S = Q K^T (64q x 32k), split 3-product ----
        f32x4 S[4][2] = {};
#pragma unroll
        for (int nt = 0; nt < 2; nt++)
#pragma unroll
            for (int ks = 0; ks < 2; ks++) {
                const long o = (krow0 + kt + nt * 16 + lm) * 64 + ks * 32 + lq * 8;
                s16x8 khf = *(const s16x8*)(Kh + o);
                s16x8 klf = *(const s16x8*)(Kl + o);
#pragma unroll
                for (int mt = 0; mt < 4; mt++) {
                    S[mt][nt] = MFMA16(qhf[mt][ks], khf, S[mt][nt], 0, 0, 0);
                    S[mt][nt] = MFMA16(qhf[mt][ks], klf, S[mt][nt], 0, 0, 0);
                    S[mt][nt] = MFMA16(qlf[mt][ks], khf, S[mt][nt], 0, 0, 0);
                }
            }
        // ---- P = exp(S/8); l partial; write P split to LDS ----
#pragma unroll
        for (int mt = 0; mt < 4; mt++)
#pragma unroll
            for (int r = 0; r < 4; r++) {
                float p0 = __expf(S[mt][0][r] * 0.125f);
                float p1 = __expf(S[mt][1][r] * 0.125f);
                float part = p0 + p1;
                part += __shfl_xor(part, 1, 64);
                part += __shfl_xor(part, 2, 64);
                part += __shfl_xor(part, 4, 64);
                part += __shfl_xor(part, 8, 64);
                lsum[mt][r] += part;
                const int q = mt * 16 + lq * 4 + r;
                UST h0 = f2bf(p0), h1 = f2bf(p1);
                myPh[q * 40 + lm] = h0;
                myPh[q * 40 + 16 + lm] = h1;
                myPl[q * 40 + lm] = f2bf(p0 - bf2f(h0));
                myPl[q * 40 + 16 + lm] = f2bf(p1 - bf2f(h1));
            }
        // ---- O += P V (P from LDS A-frags, V^T from global B-frags) ----
#pragma unroll
        for (int mt = 0; mt < 4; mt++) {
            s16x8 phf = *(const s16x8*)(myPh + (mt * 16 + lm) * 40 + lq * 8);
            s16x8 plf = *(const s16x8*)(myPl + (mt * 16 + lm) * 40 + lq * 8);
#pragma unroll
            for (int dt = 0; dt < 4; dt++) {
                const long o = vbase + (dt * 16 + lm) * 256 + kt + lq * 8;
                s16x8 vhf = *(const s16x8*)(Vth + o);
                s16x8 vlf = *(const s16x8*)(Vtl + o);
                Oacc[mt][dt] = MFMA16(phf, vhf, Oacc[mt][dt], 0, 0, 0);
                Oacc[mt][dt] = MFMA16(phf, vlf, Oacc[mt][dt], 0, 0, 0);
                Oacc[mt][dt] = MFMA16(plf, vhf, Oacc[mt][dt], 0, 0, 0);
            }
        }
    }
    // ---- normalize + write split bf16 ----
#pragma unroll
    for (int mt = 0; mt < 4; mt++)
#pragma unroll
        for (int r = 0; r < 4; r++) {
            const float inv = 1.0f / lsum[mt][r];
            const long tok = tok0 + wv * 64 + mt * 16 + lq * 4 + r;
            UST* po = oh + tok * 1024 + h * 64;
            UST* plo = ol + tok * 1024 + h * 64;
#pragma unroll
            for (int dt = 0; dt < 4; dt++) {
                float f = Oacc[mt][dt][r] * inv;
                UST hv = f2bf(f);
                po[dt * 16 + lm] = hv;
                plo[dt * 16 + lm] = f2bf(f - bf2f(hv));
            }
        }
}

// ---------------------------------------------------------------------------
// Gate (ATOMIC-FREE): logits (hi+lo fp32-grade), softmax, entropy, top-2.
// Writes combine[t][8], entbuf[t], tokexp[t] = i1 | (i2<<4).
// ---------------------------------------------------------------------------
__global__ void gate_kernel(const UST* __restrict__ lnh, const UST* __restrict__ lnl,
                            const float* __restrict__ gw, const float* __restrict__ gb,
                            float* __restrict__ combine, float* __restrict__ entbuf,
                            int* __restrict__ tokexp)
{
    const int tid = threadIdx.x;
    const int t = blockIdx.x * 4 + (tid >> 6);
    const int lane = tid & 63;
    const long row = (long)t + 2 + 4 * (t >> 12);
    const UST* ph = lnh + row * 1024;
    const UST* pl = lnl + row * 1024;
    float acc[8] = { 0, 0, 0, 0, 0, 0, 0, 0 };
    for (int c = 0; c < 16; c++) {
        int d = c * 64 + lane;
        float xv = bf2f(ph[d]) + bf2f(pl[d]);
        const float* wr = gw + (long)d * 8;
#pragma unroll
        for (int e = 0; e < 8; e++) acc[e] += xv * wr[e];
    }
#pragma unroll
    for (int e = 0; e < 8; e++)
        for (int o = 32; o > 0; o >>= 1) acc[e] += __shfl_xor(acc[e], o, 64);
    if (lane == 0) {
        float lg[8], p[8];
        float mx = -1e30f;
        for (int e = 0; e < 8; e++) { lg[e] = acc[e] + gb[e]; mx = fmaxf(mx, lg[e]); }
        float sum = 0;
        for (int e = 0; e < 8; e++) { p[e] = expf(lg[e] - mx); sum += p[e]; }
        float inv = 1.0f / sum;
        float ent = 0;
        for (int e = 0; e < 8; e++) { p[e] *= inv; ent -= p[e] * logf(p[e] + 1e-10f); }
        int i1 = 0; float v1 = -1e30f;
        for (int e = 0; e < 8; e++) if (p[e] > v1) { v1 = p[e]; i1 = e; }
        int i2 = 0; float v2 = -1e30f;
        for (int e = 0; e < 8; e++) if (e != i1 && p[e] > v2) { v2 = p[e]; i2 = e; }
        float inv2 = 1.0f / (v1 + v2);
        float cw[8] = { 0, 0, 0, 0, 0, 0, 0, 0 };
        cw[i1] = v1 * inv2; cw[i2] = v2 * inv2;
        float* co = combine + (long)t * 8;
        for (int e = 0; e < 8; e++) co[e] = cw[e];
        entbuf[t] = ent;
        tokexp[t] = i1 | (i2 << 4);
    }
}

// ---------------------------------------------------------------------------
// moe_sort: block e compacts (token,rank) pairs routed to expert e into
// perm[e*8192 ...] via ballot + wave prefix + LDS cross-wave scan.
// Bucket-internal order is arbitrary — exact either way.  One cnt8 store.
// ---------------------------------------------------------------------------
__global__ void moe_sort_kernel(const int* __restrict__ tokexp,
                                int* __restrict__ cnt8, int* __restrict__ perm)
{
    const int e = blockIdx.x;
    const int tid = threadIdx.x;
    const int lane = tid & 63, wv = tid >> 6;
    __shared__ int wsum[4];
    __shared__ int runbase;
    if (tid == 0) runbase = 0;
    __syncthreads();
    int* mybucket = perm + (e << 13);
    for (int base = 0; base < 16384; base += 256) {
        const int idx = base + tid;
        const int t = idx >> 1, r = idx & 1;
        const int te = tokexp[t];
        const int ex = r ? ((te >> 4) & 15) : (te & 15);
        const bool m = (ex == e);
        const unsigned long long mask = __ballot(m);
        if (lane == 0) wsum[wv] = __popcll(mask);
        __syncthreads();
        int wbase = runbase;
        for (int w = 0; w < 4; w++) if (w < wv) wbase += wsum[w];
        if (m) {
            const int pos = wbase + __popcll(mask & ((1ULL << lane) - 1ULL));
            const int row = t + 2 + 4 * (t >> 12);
            mybucket[pos] = row | (r << 15);
        }
        __syncthreads();
        if (tid == 0) runbase += wsum[0] + wsum[1] + wsum[2] + wsum[3];
        __syncthreads();
    }
    if (tid == 0) cnt8[e] = runbase;
}

// single-block tree reduce of entbuf -> out = 0.1 * mean
__global__ void ent_final_kernel(const float* __restrict__ entbuf, float* __restrict__ out)
{
    const int tid = threadIdx.x;
    float s = 0;
    for (int i = tid; i < 8192; i += 256) s += entbuf[i];
    for (int o = 32; o > 0; o >>= 1) s += __shfl_xor(s, o, 64);
    __shared__ float ws[4];
    if ((tid & 63) == 0) ws[tid >> 6] = s;
    __syncthreads();
    if (tid == 0) out[0] = 0.1f * (ws[0] + ws[1] + ws[2] + ws[3]) * (1.0f / 8192.0f);
}

// out += buf0 + buf1 (rank-split MoE partials), float4-vectorized
__global__ void moe_add_kernel(const float* __restrict__ b0, const float* __restrict__ b1,
                               float* __restrict__ out)
{
    const long gid = ((long)blockIdx.x * 256 + threadIdx.x) * 4;
    const float4 v0 = *(const float4*)(b0 + gid);
    const float4 v1 = *(const float4*)(b1 + gid);
    float4 o = *(float4*)(out + gid);
    o.x += v0.x + v1.x; o.y += v0.y + v1.y;
    o.z += v0.z + v1.z; o.w += v0.w + v1.w;
    *(float4*)(out + gid) = o;
}

__global__ void f32_to_bf16_kernel(const float* __restrict__ in, UST* __restrict__ out)
{
    long gid = ((long)blockIdx.x * 256 + threadIdx.x) * 4;
    float4 v = *(const float4*)(in + gid);
    out[gid] = f2bf(v.x); out[gid + 1] = f2bf(v.y);
    out[gid + 2] = f2bf(v.z); out[gid + 3] = f2bf(v.w);
}

// ===========================================================================
extern "C" void kernel_launch(void* const* d_in, const int* in_sizes, int n_in,
                              void* d_out_, int out_size, void* d_ws, size_t ws_size,
                              hipStream_t stream)
{
    const float* x      = (const float*)d_in[0];
    const float* ln1_g  = (const float*)d_in[1];
    const float* ln1_b  = (const float*)d_in[2];
    const float* qkv_w  = (const float*)d_in[3];
    const float* qkv_b  = (const float*)d_in[4];
    const float* ao_w   = (const float*)d_in[5];
    const float* ao_b   = (const float*)d_in[6];
    const float* ln2_g  = (const float*)d_in[7];
    const float* ln2_b  = (const float*)d_in[8];
    const float* conv_w = (const float*)d_in[9];
    const float* conv_b = (const float*)d_in[10];
    const float* ln3_g  = (const float*)d_in[11];
    const float* ln3_b  = (const float*)d_in[12];
    const float* gate_w = (const float*)d_in[13];
    const float* gate_b = (const float*)d_in[14];
    const float* exp_w  = (const float*)d_in[15];
    const float* exp_b  = (const float*)d_in[16];
    const float* ff_w1  = (const float*)d_in[17];
    const float* ff_b1  = (const float*)d_in[18];
    const float* ff_w2  = (const float*)d_in[19];
    const float* ff_b2  = (const float*)d_in[20];
    float* out = (float*)d_out_;

    char* ws = (char*)d_ws;
    size_t off = 0;
    auto alloc = [&](size_t bytes) -> char* {
        char* p = ws + off;
        off += (bytes + 255) & ~(size_t)255;
        return p;
    };
    UST* qkvWh = (UST*)alloc(3072 * 1024 * 2);
    UST* qkvWl = (UST*)alloc(3072 * 1024 * 2);
    UST* aoWh  = (UST*)alloc(1024 * 1024 * 2);
    UST* aoWl  = (UST*)alloc(1024 * 1024 * 2);
    UST* convCh = (UST*)alloc(1024L * 3072 * 2);   // [n=1024][k=3072] concat taps
    UST* convCl = (UST*)alloc(1024L * 3072 * 2);
    UST* expW  = (UST*)alloc(8192L * 1024 * 2);
    UST* ff1W  = (UST*)alloc(4096L * 1024 * 2);
    UST* ff2W  = (UST*)alloc(4096L * 1024 * 2);
    const size_t LN_BYTES = 8200L * 1024 * 2;
    UST* LNh = (UST*)alloc(LN_BYTES);
    UST* LNl = (UST*)alloc(LN_BYTES);
    float* combine = (float*)alloc(8192 * 8 * 4);
    float* entbuf  = (float*)alloc(8192 * 4);
    int*   tokexp  = (int*)alloc(8192 * 4);
    int*   cnt8    = (int*)alloc(256);
    int*   perm    = (int*)alloc(8 * 8192 * 4);
    char*  BIG = alloc(8192L * 3072 * 4);     // Sp during attn; moebuf; h1 later
    UST* OH = (UST*)alloc(8192L * 1024 * 2);  // attn out hi; later x3 bf16
    UST* OL = (UST*)alloc(8192L * 1024 * 2);
    if (off > ws_size) return;  // ws too small -> deliberate clean fail

    UST* Sp   = (UST*)BIG;      // [Qh|Ql|Kh|Kl|Vth|Vtl]
    float* moebuf = (float*)BIG; // [2][8192][1024] fp32 rank-split partials
    UST* h1   = (UST*)BIG;
    UST* x3h  = OH;

    // ---- weight prep (every call; ws is re-poisoned) ----
    auto nb = [](long n) { return (unsigned)((n + 255) / 256); };
    prep_t_kernel<<<dim3(48, 32), 256, 0, stream>>>(qkv_w, qkvWh, qkvWl, 3072, 1024);
    prep_t_kernel<<<dim3(16, 32), 256, 0, stream>>>(ao_w, aoWh, aoWl, 1024, 1024);
    for (int k = 0; k < 3; k++)
        prep_w_kernel<<<nb(1024L * 1024), 256, 0, stream>>>(conv_w + k, convCh, convCl,
                                                            1024, 3, 3072, 3072, k * 1024, 1024L * 1024);
    for (int e = 0; e < 8; e++)
        prep_t_kernel<<<dim3(16, 32), 256, 0, stream>>>(exp_w + (long)e * 1048576, expW + (long)e * 1048576,
                                                        nullptr, 1024, 1024);
    prep_t_kernel<<<dim3(64, 32), 256, 0, stream>>>(ff_w1, ff1W, nullptr, 4096, 1024);
    prep_t_kernel<<<dim3(16, 128), 256, 0, stream>>>(ff_w2, ff2W, nullptr, 1024, 4096);

    ln_pad_kernel<<<8, 256, 0, stream>>>(LNh, LNl);

    // ---- attention block ----
    ln_split_kernel<<<8192, 256, 0, stream>>>(x, ln1_g, ln1_b, LNh, LNl);
    gemm_bt_kernel<2, true, 0, false><<<dim3(24, 64), 256, 0, stream>>>(
        LNh, LNl, qkvWh, qkvWl, qkv_b, nullptr, nullptr, nullptr, Sp,
        8192, 3072, 1024, 1024, 2, 4, nullptr, nullptr, nullptr);
    attn_mfma_kernel<<<512, 256, 0, stream>>>(Sp, OH, OL);
    gemm_bt_kernel<0, true, 0, false><<<dim3(8, 64), 256, 0, stream>>>(
        OH, OL, aoWh, aoWl, ao_b, x, out, nullptr, nullptr,
        8192, 1024, 1024, 1024, 0, 0, nullptr, nullptr, nullptr);
    // ---- dilated conv block: ONE fused GEMM, K=3072 (3 shifted segments) ----
    ln_split_kernel<<<8192, 256, 0, stream>>>(out, ln2_g, ln2_b, LNh, LNl);
    gemm_bt_kernel<0, true, 1024, false><<<dim3(8, 64), 256, 0, stream>>>(
        LNh, LNl, convCh, convCl, conv_b, out, out, nullptr, nullptr,
        8192, 1024, 3072, 1024, 0, 4, nullptr, nullptr, nullptr);
    // ---- MoE: gate (atomic-free) -> sort -> sparse gathered expert GEMM ----
    ln_split_kernel<<<8192, 256, 0, stream>>>(out, ln3_g, ln3_b, LNh, LNl);
    gate_kernel<<<2048, 256, 0, stream>>>(LNh, LNl, gate_w, gate_b, combine, entbuf, tokexp);
    moe_sort_kernel<<<8, 256, 0, stream>>>(tokexp, cnt8, perm);
    ent_final_kernel<<<1, 256, 0, stream>>>(entbuf, out + 8388608);
    gemm_bt_kernel<3, false, 0, true><<<dim3(8, 136), 256, 0, stream>>>(
        LNh, nullptr, expW, nullptr, exp_b, nullptr, moebuf, nullptr, nullptr,
        8192, 1024, 1024, 1024, 0, 0, cnt8, perm, combine);
    moe_add_kernel<<<8192, 256, 0, stream>>>(moebuf, moebuf + 8388608, out);
    // ---- FFN ----
    f32_to_bf16_kernel<<<8192, 256, 0, stream>>>(out, x3h);
    gemm_bt_kernel<1, false, 0, false><<<dim3(32, 64), 256, 0, stream>>>(
        x3h, nullptr, ff1W, nullptr, ff_b1, nullptr, nullptr, h1, nullptr,
        8192, 4096, 1024, 1024, 0, 0, nullptr, nullptr, nullptr);
    gemm_bt_kernel<0, false, 0, false><<<dim3(8, 64), 256, 0, stream>>>(
        h1, nullptr, ff2W, nullptr, ff_b2, out, out, nullptr, nullptr,
        8192, 1024, 4096, 4096, 0, 0, nullptr, nullptr, nullptr);
}